// Round 3
// baseline (312.156 us; speedup 1.0000x reference)
//
#include <hip/hip_runtime.h>
#include <cstdint>

#define NB 2
#define NSEQ 2048
#define CDIM 768
#define NH 12
#define HD 64
#define NTOK (NB*NSEQ)        // 4096
#define QKV_COLS (3*CDIM)     // 2304

typedef short bf16x8 __attribute__((ext_vector_type(8)));   // 8 bf16 = 4 VGPR
typedef float f32x4  __attribute__((ext_vector_type(4)));
typedef short short4v __attribute__((ext_vector_type(4)));  // 8B packed store
typedef unsigned int uint2v __attribute__((ext_vector_type(2)));

#define MFMA16(a,b,c) __builtin_amdgcn_mfma_f32_16x16x32_bf16(a,b,c,0,0,0)

// fp32 -> bf16 round-to-nearest (half rounds down; bias 2^-17 rel — fine)
__device__ __forceinline__ short f2b(float f) {
    uint32_t u = __builtin_bit_cast(uint32_t, f);
    u += 0x7fffu + ((u >> 16) & 1u);
    return (short)(u >> 16);
}
// two fp32 -> packed bf16 pair (low16 = bf16(a), high16 = bf16(b)) via v_perm
__device__ __forceinline__ unsigned pack2(float a, float b) {
    unsigned ua = __builtin_bit_cast(unsigned, a) + 0x7fffu;
    unsigned ub = __builtin_bit_cast(unsigned, b) + 0x7fffu;
    return __builtin_amdgcn_perm(ub, ua, 0x07060302u);
}

// ---------------------------------------------------------------------------
// Elementwise fp32 -> bf16 (x)
// ---------------------------------------------------------------------------
__global__ __launch_bounds__(256) void convert_f32_bf16(
    const float* __restrict__ in, short* __restrict__ out, int n4)
{
    int i = blockIdx.x * 256 + threadIdx.x;
    if (i < n4) {
        float4 v = ((const float4*)in)[i];
        short4v o = { f2b(v.x), f2b(v.y), f2b(v.z), f2b(v.w) };
        ((short4v*)out)[i] = o;
    }
}

// ---------------------------------------------------------------------------
// w[K][NC] fp32 -> wt[NC][K] bf16
// ---------------------------------------------------------------------------
__global__ __launch_bounds__(256) void transpose_f32_bf16(
    const float* __restrict__ w, short* __restrict__ wt, int K, int NC)
{
    __shared__ float tile[32][33];
    const int n0 = blockIdx.x * 32, k0 = blockIdx.y * 32;
    const int t = threadIdx.x;
    #pragma unroll
    for (int i = 0; i < 4; ++i) {
        int idx = t + i * 256; int r = idx >> 5, c = idx & 31;
        tile[r][c] = w[(size_t)(k0 + r) * NC + n0 + c];
    }
    __syncthreads();
    #pragma unroll
    for (int i = 0; i < 4; ++i) {
        int idx = t + i * 256; int r = idx >> 5, c = idx & 31;
        wt[(size_t)(n0 + r) * K + k0 + c] = f2b(tile[c][r]);
    }
}

// ---------------------------------------------------------------------------
// GEMM1 (roles swapped: A = w_qkv^T rows = qkv-cols, B = x rows = tokens).
// D[row = qkv-col][col = token] -> lane holds 4 CONSECUTIVE qkv-cols (d-dims)
// at one token -> q/k stores are packed short4v. v stores scalar (transposed).
// ---------------------------------------------------------------------------
__global__ __launch_bounds__(256) void gemm_qkv(
    const short* __restrict__ A /*wqt[2304][768]*/,
    const short* __restrict__ B /*xb [4096][768]*/,
    short* __restrict__ qb, short* __restrict__ kb, short* __restrict__ vt)
{
    __shared__ short As[128][40];
    __shared__ short Bs[128][40];
    const int t = threadIdx.x;
    const int lane = t & 63, wid = t >> 6;
    const int quad = lane >> 4, l16 = lane & 15;
    const int wA = wid >> 1, wB = wid & 1;
    const int n0 = blockIdx.x * 128;   // qkv-col base
    const int m0 = blockIdx.y * 128;   // token base
    const int r0 = t >> 2, o0 = (t & 3) * 8;

    f32x4 acc[4][4] = {};
    const short* ap0 = A + (size_t)(n0 + r0) * CDIM + o0;
    const short* ap1 = ap0 + (size_t)64 * CDIM;
    const short* bp0 = B + (size_t)(m0 + r0) * CDIM + o0;
    const short* bp1 = bp0 + (size_t)64 * CDIM;

    for (int k0 = 0; k0 < CDIM; k0 += 32) {
        float4 a0 = *(const float4*)(ap0 + k0);
        float4 a1 = *(const float4*)(ap1 + k0);
        float4 b0 = *(const float4*)(bp0 + k0);
        float4 b1 = *(const float4*)(bp1 + k0);
        __syncthreads();
        *(float4*)&As[r0][o0]      = a0;
        *(float4*)&As[r0 + 64][o0] = a1;
        *(float4*)&Bs[r0][o0]      = b0;
        *(float4*)&Bs[r0 + 64][o0] = b1;
        __syncthreads();
        bf16x8 af[4], bf[4];
        #pragma unroll
        for (int i = 0; i < 4; ++i)
            af[i] = *(const bf16x8*)&As[wA*64 + i*16 + l16][quad*8];
        #pragma unroll
        for (int j = 0; j < 4; ++j)
            bf[j] = *(const bf16x8*)&Bs[wB*64 + j*16 + l16][quad*8];
        #pragma unroll
        for (int i = 0; i < 4; ++i)
            #pragma unroll
            for (int j = 0; j < 4; ++j)
                acc[i][j] = MFMA16(af[i], bf[j], acc[i][j]);
    }

    const int colbase = n0 + wA * 64;           // 64-aligned -> one (s,h)
    const int s = colbase / CDIM;
    const int h = (colbase - s * CDIM) >> 6;
    const int b = m0 >> 11;
    const size_t bh = (size_t)(b * NH + h);
    #pragma unroll
    for (int i = 0; i < 4; ++i) {
        const int d0 = i*16 + quad*4;           // 4 consecutive d per lane
        #pragma unroll
        for (int j = 0; j < 4; ++j) {
            int tok = (m0 + wB*64 + j*16 + l16) & (NSEQ - 1);
            if (s < 2) {
                short* dst = (s == 0 ? qb : kb) + (bh * NSEQ + tok) * HD + d0;
                short4v o = { f2b(acc[i][j][0]), f2b(acc[i][j][1]),
                              f2b(acc[i][j][2]), f2b(acc[i][j][3]) };
                *(short4v*)dst = o;
            } else {
                short* dst = vt + (bh * HD + d0) * NSEQ + tok;
                #pragma unroll
                for (int r = 0; r < 4; ++r)
                    dst[(size_t)r * NSEQ] = f2b(acc[i][j][r]);
            }
        }
    }
}

// ---------------------------------------------------------------------------
// Flash attention v3: Sᵀ = K·Qᵀ (lane holds Pᵀ: 4 consecutive keys), P
// exchange via wave-private LDS (packed b64 writes, b128 reads), K/V/Q frags
// loaded DIRECTLY from global (coalesced bf16x8) -> zero barriers in K-loop.
// ---------------------------------------------------------------------------
__global__ __launch_bounds__(256) void attn_kernel(
    const short* __restrict__ qb, const short* __restrict__ kb,
    const short* __restrict__ vt, const int* __restrict__ mask,
    short* __restrict__ ao)
{
    __shared__ float ms[NSEQ];                    // 8 KB, staged once
    __shared__ __align__(16) short Ps[4][16][72]; // per-wave P, 144B rows
    const int t = threadIdx.x;
    const int lane = t & 63, wid = t >> 6;
    const int quad = lane >> 4, l16 = lane & 15;
    const int q0 = blockIdx.x * 64, h = blockIdx.y, b = blockIdx.z;
    const size_t hoff = (size_t)(b*NH + h) * NSEQ * HD;
    const short* qp = qb + hoff;                  // [N][64]
    const short* kp = kb + hoff;                  // [N][64]
    const short* vp = vt + hoff;                  // [64][N]

    // stage mask row as float (one barrier for the whole kernel)
    {
        const int4* mi = (const int4*)(mask + b * NSEQ);
        #pragma unroll
        for (int i = 0; i < 2; ++i) {
            int idx = t + i * 256;
            int4 v = mi[idx];
            float4 f = { (float)v.x, (float)v.y, (float)v.z, (float)v.w };
            *(float4*)&ms[idx * 4] = f;
        }
    }
    __syncthreads();

    // Q fragments: loop-invariant, B-operand (n = query = l16)
    const short* qr = qp + (size_t)(q0 + wid*16 + l16) * HD + quad*8;
    bf16x8 qf0 = *(const bf16x8*)qr;
    bf16x8 qf1 = *(const bf16x8*)(qr + 32);

    f32x4 o_acc[4] = {};
    float l = 0.0f;

    for (int kt = 0; kt < NSEQ; kt += 64) {
        // Sᵀ tile: A = K (m = key), B = Q (n = query)
        f32x4 s[4] = {};
        #pragma unroll
        for (int jt = 0; jt < 4; ++jt) {
            const short* kr = kp + (size_t)(kt + jt*16 + l16) * HD + quad*8;
            bf16x8 kf0 = *(const bf16x8*)kr;
            bf16x8 kf1 = *(const bf16x8*)(kr + 32);
            s[jt] = MFMA16(kf0, qf0, s[jt]);
            s[jt] = MFMA16(kf1, qf1, s[jt]);
        }

        // P = exp(s/8)*mask (keys = jt*16+quad*4+r contiguous per lane)
        float part = 0.0f;
        #pragma unroll
        for (int jt = 0; jt < 4; ++jt) {
            float4 m4 = *(const float4*)&ms[kt + jt*16 + quad*4];
            float e0 = __expf(s[jt][0] * 0.125f) * m4.x;
            float e1 = __expf(s[jt][1] * 0.125f) * m4.y;
            float e2 = __expf(s[jt][2] * 0.125f) * m4.z;
            float e3 = __expf(s[jt][3] * 0.125f) * m4.w;
            part += (e0 + e1) + (e2 + e3);
            uint2v pk = { pack2(e0, e1), pack2(e2, e3) };
            *(uint2v*)&Ps[wid][l16][jt*16 + quad*4] = pk;
        }
        part += __shfl_xor(part, 16);
        part += __shfl_xor(part, 32);
        l += part;    // rowsum for query l16 of this wave

        // O += P·V : A = P rows (m = query = l16), B = vt rows (n = d)
        #pragma unroll
        for (int ks = 0; ks < 2; ++ks) {
            bf16x8 pf = *(const bf16x8*)&Ps[wid][l16][ks*32 + quad*8];
            #pragma unroll
            for (int jt = 0; jt < 4; ++jt) {
                bf16x8 vf = *(const bf16x8*)(vp + (size_t)(jt*16 + l16) * NSEQ
                                             + kt + ks*32 + quad*8);
                o_acc[jt] = MFMA16(pf, vf, o_acc[jt]);
            }
        }
    }

    // epilogue: O rows are q = quad*4+r; rowsums live at lane l16 = q
    #pragma unroll
    for (int r = 0; r < 4; ++r) {
        float lr = __shfl(l, quad*4 + r, 64);
        float inv = 1.0f / lr;
        int tok = b * NSEQ + q0 + wid*16 + quad*4 + r;
        #pragma unroll
        for (int jt = 0; jt < 4; ++jt)
            ao[(size_t)tok * CDIM + h*HD + jt*16 + l16] = f2b(o_acc[jt][r] * inv);
    }
}

// ---------------------------------------------------------------------------
// GEMM2 (roles swapped): lane holds 4 consecutive out-cols -> float4 stores.
// ---------------------------------------------------------------------------
__global__ __launch_bounds__(256) void gemm_proj(
    const short* __restrict__ A /*wpt[768][768]*/,
    const short* __restrict__ B /*ao [4096][768]*/,
    const float* __restrict__ bias, float* __restrict__ out)
{
    __shared__ short As[128][40];
    __shared__ short Bs[128][40];
    const int t = threadIdx.x;
    const int lane = t & 63, wid = t >> 6;
    const int quad = lane >> 4, l16 = lane & 15;
    const int wA = wid >> 1, wB = wid & 1;
    const int n0 = blockIdx.x * 128;   // out-col base
    const int m0 = blockIdx.y * 128;   // token base
    const int r0 = t >> 2, o0 = (t & 3) * 8;

    f32x4 acc[4][4] = {};
    const short* ap0 = A + (size_t)(n0 + r0) * CDIM + o0;
    const short* ap1 = ap0 + (size_t)64 * CDIM;
    const short* bp0 = B + (size_t)(m0 + r0) * CDIM + o0;
    const short* bp1 = bp0 + (size_t)64 * CDIM;

    for (int k0 = 0; k0 < CDIM; k0 += 32) {
        float4 a0 = *(const float4*)(ap0 + k0);
        float4 a1 = *(const float4*)(ap1 + k0);
        float4 b0 = *(const float4*)(bp0 + k0);
        float4 b1 = *(const float4*)(bp1 + k0);
        __syncthreads();
        *(float4*)&As[r0][o0]      = a0;
        *(float4*)&As[r0 + 64][o0] = a1;
        *(float4*)&Bs[r0][o0]      = b0;
        *(float4*)&Bs[r0 + 64][o0] = b1;
        __syncthreads();
        bf16x8 af[4], bf[4];
        #pragma unroll
        for (int i = 0; i < 4; ++i)
            af[i] = *(const bf16x8*)&As[wA*64 + i*16 + l16][quad*8];
        #pragma unroll
        for (int j = 0; j < 4; ++j)
            bf[j] = *(const bf16x8*)&Bs[wB*64 + j*16 + l16][quad*8];
        #pragma unroll
        for (int i = 0; i < 4; ++i)
            #pragma unroll
            for (int j = 0; j < 4; ++j)
                acc[i][j] = MFMA16(af[i], bf[j], acc[i][j]);
    }

    #pragma unroll
    for (int i = 0; i < 4; ++i) {
        int col0 = n0 + wA*64 + i*16 + quad*4;   // 4 consecutive out-cols
        float4 bias4 = *(const float4*)&bias[col0];
        #pragma unroll
        for (int j = 0; j < 4; ++j) {
            int tok = m0 + wB*64 + j*16 + l16;
            float4 o = { acc[i][j][0] + bias4.x, acc[i][j][1] + bias4.y,
                         acc[i][j][2] + bias4.z, acc[i][j][3] + bias4.w };
            *(float4*)(out + (size_t)tok * CDIM + col0) = o;
        }
    }
}

extern "C" void kernel_launch(void* const* d_in, const int* in_sizes, int n_in,
                              void* d_out, int out_size, void* d_ws, size_t ws_size,
                              hipStream_t stream)
{
    const float* x      = (const float*)d_in[0];
    const int*   mask   = (const int*)d_in[1];
    const float* w_qkv  = (const float*)d_in[2];
    const float* w_proj = (const float*)d_in[3];
    const float* b_proj = (const float*)d_in[4];
    float* out = (float*)d_out;

    const size_t SZ = (size_t)NTOK * CDIM;       // 3,145,728
    short* xb  = (short*)d_ws;                   // [4096][768]
    short* wqt = xb  + SZ;                       // [2304][768]
    short* wpt = wqt + (size_t)QKV_COLS * CDIM;  // [768][768]
    short* qb  = wpt + (size_t)CDIM * CDIM;      // [BH][N][64]
    short* kb  = qb  + SZ;                       // [BH][N][64]
    short* vt  = kb  + SZ;                       // [BH][64][N]
    short* ao  = vt  + SZ;                       // [4096][768]

    dim3 blk(256);
    convert_f32_bf16<<<(SZ/4 + 255)/256, blk, 0, stream>>>(x, xb, (int)(SZ/4));
    transpose_f32_bf16<<<dim3(QKV_COLS/32, CDIM/32), blk, 0, stream>>>(w_qkv, wqt, CDIM, QKV_COLS);
    transpose_f32_bf16<<<dim3(CDIM/32, CDIM/32),     blk, 0, stream>>>(w_proj, wpt, CDIM, CDIM);
    gemm_qkv<<<dim3(QKV_COLS/128, NTOK/128), blk, 0, stream>>>(wqt, xb, qb, kb, vt);
    attn_kernel<<<dim3(NSEQ/64, NH, NB), blk, 0, stream>>>(qb, kb, vt, mask, ao);
    gemm_proj<<<dim3(CDIM/128, NTOK/128), blk, 0, stream>>>(wpt, ao, b_proj, out);
}

// Round 4
// 232.558 us; speedup vs baseline: 1.3423x; 1.3423x over previous
//
#include <hip/hip_runtime.h>
#include <cstdint>

#define NB 2
#define NSEQ 2048
#define CDIM 768
#define NH 12
#define HD 64
#define NTOK (NB*NSEQ)        // 4096
#define QKV_COLS (3*CDIM)     // 2304

typedef short bf16x8 __attribute__((ext_vector_type(8)));   // 8 bf16 = 4 VGPR
typedef short bf16x4 __attribute__((ext_vector_type(4)));
typedef float f32x4  __attribute__((ext_vector_type(4)));
typedef short short4v __attribute__((ext_vector_type(4)));
typedef unsigned int uint4v __attribute__((ext_vector_type(4)));

#define MFMA16(a,b,c) __builtin_amdgcn_mfma_f32_16x16x32_bf16(a,b,c,0,0,0)

// fp32 -> bf16 round-to-nearest
__device__ __forceinline__ short f2b(float f) {
    uint32_t u = __builtin_bit_cast(uint32_t, f);
    u += 0x7fffu + ((u >> 16) & 1u);
    return (short)(u >> 16);
}
// two fp32 -> packed bf16 pair via v_perm
__device__ __forceinline__ unsigned pack2(float a, float b) {
    unsigned ua = __builtin_bit_cast(unsigned, a) + 0x7fffu;
    unsigned ub = __builtin_bit_cast(unsigned, b) + 0x7fffu;
    return __builtin_amdgcn_perm(ub, ua, 0x07060302u);
}
// async global->LDS, 16B per lane; lds base must be wave-uniform
__device__ __forceinline__ void gll16(const short* g, short* l) {
    __builtin_amdgcn_global_load_lds(
        (const __attribute__((address_space(1))) unsigned int*)g,
        (__attribute__((address_space(3))) unsigned int*)l, 16, 0, 0);
}

// ---------------------------------------------------------------------------
__global__ __launch_bounds__(256) void convert_f32_bf16(
    const float* __restrict__ in, short* __restrict__ out, int n4)
{
    int i = blockIdx.x * 256 + threadIdx.x;
    if (i < n4) {
        float4 v = ((const float4*)in)[i];
        short4v o = { f2b(v.x), f2b(v.y), f2b(v.z), f2b(v.w) };
        ((short4v*)out)[i] = o;
    }
}

// ---------------------------------------------------------------------------
__global__ __launch_bounds__(256) void transpose_f32_bf16(
    const float* __restrict__ w, short* __restrict__ wt, int K, int NC)
{
    __shared__ float tile[32][33];
    const int n0 = blockIdx.x * 32, k0 = blockIdx.y * 32;
    const int t = threadIdx.x;
    #pragma unroll
    for (int i = 0; i < 4; ++i) {
        int idx = t + i * 256; int r = idx >> 5, c = idx & 31;
        tile[r][c] = w[(size_t)(k0 + r) * NC + n0 + c];
    }
    __syncthreads();
    #pragma unroll
    for (int i = 0; i < 4; ++i) {
        int idx = t + i * 256; int r = idx >> 5, c = idx & 31;
        wt[(size_t)(n0 + r) * K + k0 + c] = f2b(tile[c][r]);
    }
}

// ---------------------------------------------------------------------------
// GEMM1 (m97-style): global_load_lds staging, unpadded 64B-row LDS, BK=32.
// A = wqt (qkv-cols), B = xb (tokens). Epilogue as round 3.
// ---------------------------------------------------------------------------
__global__ __launch_bounds__(256) void gemm_qkv(
    const short* __restrict__ A /*wqt[2304][768]*/,
    const short* __restrict__ B /*xb [4096][768]*/,
    short* __restrict__ qb, short* __restrict__ kb, short* __restrict__ vt)
{
    __shared__ short As[128 * 32];
    __shared__ short Bs[128 * 32];
    const int t = threadIdx.x;
    const int lane = t & 63, wid = t >> 6;
    const int quad = lane >> 4, l16 = lane & 15;
    const int wA = wid >> 1, wB = wid & 1;
    const int n0 = blockIdx.x * 128;   // qkv-col base
    const int m0 = blockIdx.y * 128;   // token base

    const int srow = wid * 16 + (lane >> 2), schunk = (lane & 3) * 8;
    const short* ag0 = A + (size_t)(n0 + srow) * CDIM + schunk;
    const short* ag1 = ag0 + (size_t)64 * CDIM;
    const short* bg0 = B + (size_t)(m0 + srow) * CDIM + schunk;
    const short* bg1 = bg0 + (size_t)64 * CDIM;
    short* asl0 = &As[(wid * 16) * 32];
    short* asl1 = &As[(wid * 16 + 64) * 32];
    short* bsl0 = &Bs[(wid * 16) * 32];
    short* bsl1 = &Bs[(wid * 16 + 64) * 32];

    f32x4 acc[4][4] = {};
    for (int k0 = 0; k0 < CDIM; k0 += 32) {
        __syncthreads();               // prior frag reads done
        gll16(ag0 + k0, asl0);
        gll16(ag1 + k0, asl1);
        gll16(bg0 + k0, bsl0);
        gll16(bg1 + k0, bsl1);
        __syncthreads();               // vmcnt(0) drain lands the data
        bf16x8 af[4], bf[4];
        #pragma unroll
        for (int i = 0; i < 4; ++i)
            af[i] = *(const bf16x8*)&As[(wA*64 + i*16 + l16) * 32 + quad*8];
        #pragma unroll
        for (int j = 0; j < 4; ++j)
            bf[j] = *(const bf16x8*)&Bs[(wB*64 + j*16 + l16) * 32 + quad*8];
        #pragma unroll
        for (int i = 0; i < 4; ++i)
            #pragma unroll
            for (int j = 0; j < 4; ++j)
                acc[i][j] = MFMA16(af[i], bf[j], acc[i][j]);
    }

    const int colbase = n0 + wA * 64;
    const int s = colbase / CDIM;
    const int h = (colbase - s * CDIM) >> 6;
    const int b = m0 >> 11;
    const size_t bh = (size_t)(b * NH + h);
    #pragma unroll
    for (int i = 0; i < 4; ++i) {
        const int d0 = i*16 + quad*4;
        #pragma unroll
        for (int j = 0; j < 4; ++j) {
            int tok = (m0 + wB*64 + j*16 + l16) & (NSEQ - 1);
            if (s < 2) {
                short* dst = (s == 0 ? qb : kb) + (bh * NSEQ + tok) * HD + d0;
                short4v o = { f2b(acc[i][j][0]), f2b(acc[i][j][1]),
                              f2b(acc[i][j][2]), f2b(acc[i][j][3]) };
                *(short4v*)dst = o;
            } else {
                short* dst = vt + (bh * HD + d0) * NSEQ + tok;
                #pragma unroll
                for (int r = 0; r < 4; ++r)
                    dst[(size_t)r * NSEQ] = f2b(acc[i][j][r]);
            }
        }
    }
}

// ---------------------------------------------------------------------------
// Flash attention v4: barrier-free, LDS-free main loop.
// Each wave owns a 16-key slice of each 64-key tile (disjoint loads).
// Sᵀ = K·Qᵀ -> lane holds P[key=quad*4+r][query=l16] = exactly the B-operand
// layout for PV if two 64-tiles are fused per iteration with a per-quad
// k-permutation (A-side V frags loaded to match). Cross-wave O/rowsum
// reduction once in the epilogue.
// ---------------------------------------------------------------------------
__global__ __launch_bounds__(256) void attn_kernel(
    const short* __restrict__ qb, const short* __restrict__ kb,
    const short* __restrict__ vt, const int* __restrict__ mask,
    short* __restrict__ ao)
{
    __shared__ float Ob[64][68];     // O^T partial-sum buffer [d][q]
    __shared__ float lsum[4][64];    // per-wave rowsum partials
    const int t = threadIdx.x;
    const int lane = t & 63, wid = t >> 6;
    const int quad = lane >> 4, l16 = lane & 15;
    const int q0 = blockIdx.x * 64, h = blockIdx.y, b = blockIdx.z;
    const size_t hoff = (size_t)(b*NH + h) * NSEQ * HD;
    const short* qp = qb + hoff;     // [N][64]
    const short* kp = kb + hoff;     // [N][64]
    const short* vp = vt + hoff;     // [64][N]
    const int* mp = mask + b * NSEQ;

    // Q fragments (B-operand, all 64 queries), loop-invariant: 32 VGPRs
    bf16x8 qf[4][2];
    #pragma unroll
    for (int jt = 0; jt < 4; ++jt) {
        const short* qr = qp + (size_t)(q0 + jt*16 + l16) * HD + quad*8;
        qf[jt][0] = *(const bf16x8*)qr;
        qf[jt][1] = *(const bf16x8*)(qr + 32);
    }

    f32x4 o_acc[4][4] = {};          // [it=d-tile][jt=q-tile], O^T partials
    float l[4] = {0.f, 0.f, 0.f, 0.f};
    const int kbase = wid * 16 + quad * 4;   // lane's first key within a tile

    for (int kt = 0; kt < NSEQ; kt += 128) {
        // ---- S phase: two 64-key tiles, wave's 16-key slice each ----
        f32x4 s0[4] = {}, s1[4] = {};
        {
            const short* kr = kp + (size_t)(kt + wid*16 + l16) * HD + quad*8;
            bf16x8 kf0 = *(const bf16x8*)kr;
            bf16x8 kf1 = *(const bf16x8*)(kr + 32);
            #pragma unroll
            for (int jt = 0; jt < 4; ++jt) {
                s0[jt] = MFMA16(kf0, qf[jt][0], s0[jt]);
                s0[jt] = MFMA16(kf1, qf[jt][1], s0[jt]);
            }
        }
        {
            const short* kr = kp + (size_t)(kt + 64 + wid*16 + l16) * HD + quad*8;
            bf16x8 kf0 = *(const bf16x8*)kr;
            bf16x8 kf1 = *(const bf16x8*)(kr + 32);
            #pragma unroll
            for (int jt = 0; jt < 4; ++jt) {
                s1[jt] = MFMA16(kf0, qf[jt][0], s1[jt]);
                s1[jt] = MFMA16(kf1, qf[jt][1], s1[jt]);
            }
        }

        // ---- mask, exp (faithful: no max-sub), rowsum partial, pack ----
        int4 mi0 = *(const int4*)(mp + kt + kbase);
        int4 mi1 = *(const int4*)(mp + kt + 64 + kbase);
        float4 m0 = {(float)mi0.x, (float)mi0.y, (float)mi0.z, (float)mi0.w};
        float4 m1 = {(float)mi1.x, (float)mi1.y, (float)mi1.z, (float)mi1.w};
        bf16x8 pb[4];
        #pragma unroll
        for (int jt = 0; jt < 4; ++jt) {
            float e0 = __expf(s0[jt][0] * 0.125f) * m0.x;
            float e1 = __expf(s0[jt][1] * 0.125f) * m0.y;
            float e2 = __expf(s0[jt][2] * 0.125f) * m0.z;
            float e3 = __expf(s0[jt][3] * 0.125f) * m0.w;
            float f0 = __expf(s1[jt][0] * 0.125f) * m1.x;
            float f1 = __expf(s1[jt][1] * 0.125f) * m1.y;
            float f2 = __expf(s1[jt][2] * 0.125f) * m1.z;
            float f3 = __expf(s1[jt][3] * 0.125f) * m1.w;
            l[jt] += ((e0 + e1) + (e2 + e3)) + ((f0 + f1) + (f2 + f3));
            uint4v pk = { pack2(e0, e1), pack2(e2, e3),
                          pack2(f0, f1), pack2(f2, f3) };
            pb[jt] = __builtin_bit_cast(bf16x8, pk);
        }

        // ---- PV: A = V^T frags (k-permuted to match pb), 16 MFMA ----
        #pragma unroll
        for (int it = 0; it < 4; ++it) {
            const short* vr = vp + (size_t)(it*16 + l16) * NSEQ + kt + kbase;
            bf16x4 lo = *(const bf16x4*)vr;          // tile-0 keys kbase..+3
            bf16x4 hi = *(const bf16x4*)(vr + 64);   // tile-1 keys
            bf16x8 vf = __builtin_shufflevector(lo, hi, 0,1,2,3,4,5,6,7);
            #pragma unroll
            for (int jt = 0; jt < 4; ++jt)
                o_acc[it][jt] = MFMA16(vf, pb[jt], o_acc[it][jt]);
        }
    }

    // ---- epilogue: rowsum reduce (quad then cross-wave via LDS) ----
    #pragma unroll
    for (int jt = 0; jt < 4; ++jt) {
        l[jt] += __shfl_xor(l[jt], 16);
        l[jt] += __shfl_xor(l[jt], 32);
        if (quad == 0) lsum[wid][jt*16 + l16] = l[jt];
    }
    // sequential cross-wave O^T accumulate (once per block)
    for (int w = 0; w < 4; ++w) {
        __syncthreads();
        if (wid == w) {
            #pragma unroll
            for (int it = 0; it < 4; ++it)
                #pragma unroll
                for (int jt = 0; jt < 4; ++jt)
                    #pragma unroll
                    for (int r = 0; r < 4; ++r) {
                        if (w == 0)
                            Ob[it*16 + quad*4 + r][jt*16 + l16] = o_acc[it][jt][r];
                        else
                            Ob[it*16 + quad*4 + r][jt*16 + l16] += o_acc[it][jt][r];
                    }
        }
    }
    __syncthreads();

    // normalize + store: thread -> (q = t>>2, 16 d-channels)
    {
        const int ql = t >> 2, dc = (t & 3) * 16;
        float inv = 1.0f / (((lsum[0][ql] + lsum[1][ql]) +
                             (lsum[2][ql] + lsum[3][ql])));
        bf16x8 o8a, o8b;
        #pragma unroll
        for (int d = 0; d < 8; ++d) o8a[d] = f2b(Ob[dc + d][ql] * inv);
        #pragma unroll
        for (int d = 0; d < 8; ++d) o8b[d] = f2b(Ob[dc + 8 + d][ql] * inv);
        int tok = b * NSEQ + q0 + ql;
        short* dst = ao + (size_t)tok * CDIM + h * HD + dc;
        *(bf16x8*)dst = o8a;
        *(bf16x8*)(dst + 8) = o8b;
    }
}

// ---------------------------------------------------------------------------
// GEMM2 (m97-style staging): out = ao @ w_proj + bias, fp32 out.
// ---------------------------------------------------------------------------
__global__ __launch_bounds__(256) void gemm_proj(
    const short* __restrict__ A /*wpt[768][768]*/,
    const short* __restrict__ B /*ao [4096][768]*/,
    const float* __restrict__ bias, float* __restrict__ out)
{
    __shared__ short As[128 * 32];
    __shared__ short Bs[128 * 32];
    const int t = threadIdx.x;
    const int lane = t & 63, wid = t >> 6;
    const int quad = lane >> 4, l16 = lane & 15;
    const int wA = wid >> 1, wB = wid & 1;
    const int n0 = blockIdx.x * 128;
    const int m0 = blockIdx.y * 128;

    const int srow = wid * 16 + (lane >> 2), schunk = (lane & 3) * 8;
    const short* ag0 = A + (size_t)(n0 + srow) * CDIM + schunk;
    const short* ag1 = ag0 + (size_t)64 * CDIM;
    const short* bg0 = B + (size_t)(m0 + srow) * CDIM + schunk;
    const short* bg1 = bg0 + (size_t)64 * CDIM;
    short* asl0 = &As[(wid * 16) * 32];
    short* asl1 = &As[(wid * 16 + 64) * 32];
    short* bsl0 = &Bs[(wid * 16) * 32];
    short* bsl1 = &Bs[(wid * 16 + 64) * 32];

    f32x4 acc[4][4] = {};
    for (int k0 = 0; k0 < CDIM; k0 += 32) {
        __syncthreads();
        gll16(ag0 + k0, asl0);
        gll16(ag1 + k0, asl1);
        gll16(bg0 + k0, bsl0);
        gll16(bg1 + k0, bsl1);
        __syncthreads();
        bf16x8 af[4], bf[4];
        #pragma unroll
        for (int i = 0; i < 4; ++i)
            af[i] = *(const bf16x8*)&As[(wA*64 + i*16 + l16) * 32 + quad*8];
        #pragma unroll
        for (int j = 0; j < 4; ++j)
            bf[j] = *(const bf16x8*)&Bs[(wB*64 + j*16 + l16) * 32 + quad*8];
        #pragma unroll
        for (int i = 0; i < 4; ++i)
            #pragma unroll
            for (int j = 0; j < 4; ++j)
                acc[i][j] = MFMA16(af[i], bf[j], acc[i][j]);
    }

    #pragma unroll
    for (int i = 0; i < 4; ++i) {
        int col0 = n0 + wA*64 + i*16 + quad*4;
        float4 bias4 = *(const float4*)&bias[col0];
        #pragma unroll
        for (int j = 0; j < 4; ++j) {
            int tok = m0 + wB*64 + j*16 + l16;
            float4 o = { acc[i][j][0] + bias4.x, acc[i][j][1] + bias4.y,
                         acc[i][j][2] + bias4.z, acc[i][j][3] + bias4.w };
            *(float4*)(out + (size_t)tok * CDIM + col0) = o;
        }
    }
}

extern "C" void kernel_launch(void* const* d_in, const int* in_sizes, int n_in,
                              void* d_out, int out_size, void* d_ws, size_t ws_size,
                              hipStream_t stream)
{
    const float* x      = (const float*)d_in[0];
    const int*   mask   = (const int*)d_in[1];
    const float* w_qkv  = (const float*)d_in[2];
    const float* w_proj = (const float*)d_in[3];
    const float* b_proj = (const float*)d_in[4];
    float* out = (float*)d_out;

    const size_t SZ = (size_t)NTOK * CDIM;       // 3,145,728
    short* xb  = (short*)d_ws;                   // [4096][768]
    short* wqt = xb  + SZ;                       // [2304][768]
    short* wpt = wqt + (size_t)QKV_COLS * CDIM;  // [768][768]
    short* qb  = wpt + (size_t)CDIM * CDIM;      // [BH][N][64]
    short* kb  = qb  + SZ;                       // [BH][N][64]
    short* vt  = kb  + SZ;                       // [BH][64][N]
    short* ao  = vt  + SZ;                       // [4096][768]

    dim3 blk(256);
    convert_f32_bf16<<<(SZ/4 + 255)/256, blk, 0, stream>>>(x, xb, (int)(SZ/4));
    transpose_f32_bf16<<<dim3(QKV_COLS/32, CDIM/32), blk, 0, stream>>>(w_qkv, wqt, CDIM, QKV_COLS);
    transpose_f32_bf16<<<dim3(CDIM/32, CDIM/32),     blk, 0, stream>>>(w_proj, wpt, CDIM, CDIM);
    gemm_qkv<<<dim3(QKV_COLS/128, NTOK/128), blk, 0, stream>>>(wqt, xb, qb, kb, vt);
    attn_kernel<<<dim3(NSEQ/64, NH, NB), blk, 0, stream>>>(qb, kb, vt, mask, ao);
    gemm_proj<<<dim3(CDIM/128, NTOK/128), blk, 0, stream>>>(wpt, ao, b_proj, out);
}

// Round 5
// 212.418 us; speedup vs baseline: 1.4695x; 1.0948x over previous
//
#include <hip/hip_runtime.h>
#include <cstdint>

#define NB 2
#define NSEQ 2048
#define CDIM 768
#define NH 12
#define HD 64
#define NTOK (NB*NSEQ)        // 4096
#define QKV_COLS (3*CDIM)     // 2304
#define NBLK ((NSEQ/64)*NH*NB) // 768 attn blocks

typedef short bf16x8 __attribute__((ext_vector_type(8)));   // 8 bf16 = 4 VGPR
typedef short bf16x4 __attribute__((ext_vector_type(4)));
typedef float f32x4  __attribute__((ext_vector_type(4)));
typedef short short4v __attribute__((ext_vector_type(4)));
typedef unsigned int uint4v __attribute__((ext_vector_type(4)));

#define MFMA16(a,b,c) __builtin_amdgcn_mfma_f32_16x16x32_bf16(a,b,c,0,0,0)

__device__ __forceinline__ short f2b(float f) {
    uint32_t u = __builtin_bit_cast(uint32_t, f);
    u += 0x7fffu + ((u >> 16) & 1u);
    return (short)(u >> 16);
}
__device__ __forceinline__ unsigned pack2(float a, float b) {
    unsigned ua = __builtin_bit_cast(unsigned, a) + 0x7fffu;
    unsigned ub = __builtin_bit_cast(unsigned, b) + 0x7fffu;
    return __builtin_amdgcn_perm(ub, ua, 0x07060302u);
}
__device__ __forceinline__ void gll16(const short* g, short* l) {
    __builtin_amdgcn_global_load_lds(
        (const __attribute__((address_space(1))) unsigned int*)g,
        (__attribute__((address_space(3))) unsigned int*)l, 16, 0, 0);
}

// ---------------------------------------------------------------------------
__global__ __launch_bounds__(256) void convert_f32_bf16(
    const float* __restrict__ in, short* __restrict__ out, int n4)
{
    int i = blockIdx.x * 256 + threadIdx.x;
    if (i < n4) {
        float4 v = ((const float4*)in)[i];
        short4v o = { f2b(v.x), f2b(v.y), f2b(v.z), f2b(v.w) };
        ((short4v*)out)[i] = o;
    }
}

// ---------------------------------------------------------------------------
__global__ __launch_bounds__(256) void transpose_f32_bf16(
    const float* __restrict__ w, short* __restrict__ wt, int K, int NC)
{
    __shared__ float tile[32][33];
    const int n0 = blockIdx.x * 32, k0 = blockIdx.y * 32;
    const int t = threadIdx.x;
    #pragma unroll
    for (int i = 0; i < 4; ++i) {
        int idx = t + i * 256; int r = idx >> 5, c = idx & 31;
        tile[r][c] = w[(size_t)(k0 + r) * NC + n0 + c];
    }
    __syncthreads();
    #pragma unroll
    for (int i = 0; i < 4; ++i) {
        int idx = t + i * 256; int r = idx >> 5, c = idx & 31;
        wt[(size_t)(n0 + r) * K + k0 + c] = f2b(tile[c][r]);
    }
}

// ---------------------------------------------------------------------------
// GEMM1 (m97-style, unchanged from round 4)
// ---------------------------------------------------------------------------
__global__ __launch_bounds__(256) void gemm_qkv(
    const short* __restrict__ A /*wqt[2304][768]*/,
    const short* __restrict__ B /*xb [4096][768]*/,
    short* __restrict__ qb, short* __restrict__ kb, short* __restrict__ vt)
{
    __shared__ short As[128 * 32];
    __shared__ short Bs[128 * 32];
    const int t = threadIdx.x;
    const int lane = t & 63, wid = t >> 6;
    const int quad = lane >> 4, l16 = lane & 15;
    const int wA = wid >> 1, wB = wid & 1;
    const int n0 = blockIdx.x * 128;
    const int m0 = blockIdx.y * 128;

    const int srow = wid * 16 + (lane >> 2), schunk = (lane & 3) * 8;
    const short* ag0 = A + (size_t)(n0 + srow) * CDIM + schunk;
    const short* ag1 = ag0 + (size_t)64 * CDIM;
    const short* bg0 = B + (size_t)(m0 + srow) * CDIM + schunk;
    const short* bg1 = bg0 + (size_t)64 * CDIM;
    short* asl0 = &As[(wid * 16) * 32];
    short* asl1 = &As[(wid * 16 + 64) * 32];
    short* bsl0 = &Bs[(wid * 16) * 32];
    short* bsl1 = &Bs[(wid * 16 + 64) * 32];

    f32x4 acc[4][4] = {};
    for (int k0 = 0; k0 < CDIM; k0 += 32) {
        __syncthreads();
        gll16(ag0 + k0, asl0);
        gll16(ag1 + k0, asl1);
        gll16(bg0 + k0, bsl0);
        gll16(bg1 + k0, bsl1);
        __syncthreads();
        bf16x8 af[4], bf[4];
        #pragma unroll
        for (int i = 0; i < 4; ++i)
            af[i] = *(const bf16x8*)&As[(wA*64 + i*16 + l16) * 32 + quad*8];
        #pragma unroll
        for (int j = 0; j < 4; ++j)
            bf[j] = *(const bf16x8*)&Bs[(wB*64 + j*16 + l16) * 32 + quad*8];
        #pragma unroll
        for (int i = 0; i < 4; ++i)
            #pragma unroll
            for (int j = 0; j < 4; ++j)
                acc[i][j] = MFMA16(af[i], bf[j], acc[i][j]);
    }

    const int colbase = n0 + wA * 64;
    const int s = colbase / CDIM;
    const int h = (colbase - s * CDIM) >> 6;
    const int b = m0 >> 11;
    const size_t bh = (size_t)(b * NH + h);
    #pragma unroll
    for (int i = 0; i < 4; ++i) {
        const int d0 = i*16 + quad*4;
        #pragma unroll
        for (int j = 0; j < 4; ++j) {
            int tok = (m0 + wB*64 + j*16 + l16) & (NSEQ - 1);
            if (s < 2) {
                short* dst = (s == 0 ? qb : kb) + (bh * NSEQ + tok) * HD + d0;
                short4v o = { f2b(acc[i][j][0]), f2b(acc[i][j][1]),
                              f2b(acc[i][j][2]), f2b(acc[i][j][3]) };
                *(short4v*)dst = o;
            } else {
                short* dst = vt + (bh * HD + d0) * NSEQ + tok;
                #pragma unroll
                for (int r = 0; r < 4; ++r)
                    dst[(size_t)r * NSEQ] = f2b(acc[i][j][r]);
            }
        }
    }
}

// ---------------------------------------------------------------------------
// Flash attention v5: v4 structure + one-deep register prefetch (ping-pong)
// + XCD-aware swizzle (each XCD owns 3 (b,h) pairs -> K/V L2-resident).
// ---------------------------------------------------------------------------
// load tile (KT) K-frags / V-frags / mask into named regs
#define LOADT(KT, k00,k01,k10,k11, vl,vh, mm0,mm1) do {                          \
    const short* kr0_ = kp + (size_t)((KT) + kslice) * HD + quad*8;              \
    k00 = *(const bf16x8*)kr0_;                                                  \
    k01 = *(const bf16x8*)(kr0_ + 32);                                           \
    const short* kr1_ = kr0_ + (size_t)64 * HD;                                  \
    k10 = *(const bf16x8*)kr1_;                                                  \
    k11 = *(const bf16x8*)(kr1_ + 32);                                           \
    const short* vr_ = vp + (size_t)l16 * NSEQ + (KT) + kbase;                   \
    vl[0] = *(const bf16x4*)vr_;                                                 \
    vh[0] = *(const bf16x4*)(vr_ + 64);                                          \
    vl[1] = *(const bf16x4*)(vr_ + 16*NSEQ);                                     \
    vh[1] = *(const bf16x4*)(vr_ + 16*NSEQ + 64);                                \
    vl[2] = *(const bf16x4*)(vr_ + 32*NSEQ);                                     \
    vh[2] = *(const bf16x4*)(vr_ + 32*NSEQ + 64);                                \
    vl[3] = *(const bf16x4*)(vr_ + 48*NSEQ);                                     \
    vh[3] = *(const bf16x4*)(vr_ + 48*NSEQ + 64);                                \
    mm0 = *(const int4*)(mp + (KT) + kbase);                                     \
    mm1 = *(const int4*)(mp + (KT) + 64 + kbase);                                \
} while (0)

// S -> exp*mask -> rowsum -> pack -> PV for one 128-key tile-pair
#define BODYT(k00,k01,k10,k11, vl,vh, mm0,mm1) do {                              \
    f32x4 s0_[4] = {}, s1_[4] = {};                                              \
    _Pragma("unroll")                                                            \
    for (int jt = 0; jt < 4; ++jt) {                                             \
        s0_[jt] = MFMA16(k00, qf[jt][0], s0_[jt]);                               \
        s0_[jt] = MFMA16(k01, qf[jt][1], s0_[jt]);                               \
        s1_[jt] = MFMA16(k10, qf[jt][0], s1_[jt]);                               \
        s1_[jt] = MFMA16(k11, qf[jt][1], s1_[jt]);                               \
    }                                                                            \
    float4 m0_ = {(float)mm0.x, (float)mm0.y, (float)mm0.z, (float)mm0.w};       \
    float4 m1_ = {(float)mm1.x, (float)mm1.y, (float)mm1.z, (float)mm1.w};       \
    bf16x8 pb_[4];                                                               \
    _Pragma("unroll")                                                            \
    for (int jt = 0; jt < 4; ++jt) {                                             \
        float e0 = __expf(s0_[jt][0] * 0.125f) * m0_.x;                          \
        float e1 = __expf(s0_[jt][1] * 0.125f) * m0_.y;                          \
        float e2 = __expf(s0_[jt][2] * 0.125f) * m0_.z;                          \
        float e3 = __expf(s0_[jt][3] * 0.125f) * m0_.w;                          \
        float f0 = __expf(s1_[jt][0] * 0.125f) * m1_.x;                          \
        float f1 = __expf(s1_[jt][1] * 0.125f) * m1_.y;                          \
        float f2 = __expf(s1_[jt][2] * 0.125f) * m1_.z;                          \
        float f3 = __expf(s1_[jt][3] * 0.125f) * m1_.w;                          \
        l[jt] += ((e0 + e1) + (e2 + e3)) + ((f0 + f1) + (f2 + f3));              \
        uint4v pk_ = { pack2(e0, e1), pack2(e2, e3),                             \
                       pack2(f0, f1), pack2(f2, f3) };                           \
        pb_[jt] = __builtin_bit_cast(bf16x8, pk_);                               \
    }                                                                            \
    _Pragma("unroll")                                                            \
    for (int it = 0; it < 4; ++it) {                                             \
        bf16x8 vf_ = __builtin_shufflevector(vl[it], vh[it], 0,1,2,3,4,5,6,7);   \
        _Pragma("unroll")                                                        \
        for (int jt = 0; jt < 4; ++jt)                                           \
            o_acc[it][jt] = MFMA16(vf_, pb_[jt], o_acc[it][jt]);                 \
    }                                                                            \
} while (0)

__global__ __launch_bounds__(256) void attn_kernel(
    const short* __restrict__ qb, const short* __restrict__ kb,
    const short* __restrict__ vt, const int* __restrict__ mask,
    short* __restrict__ ao)
{
    __shared__ float Ob[64][68];
    __shared__ float lsum[4][64];
    const int t = threadIdx.x;
    const int lane = t & 63, wid = t >> 6;
    const int quad = lane >> 4, l16 = lane & 15;
    // XCD swizzle: XCD = id%8 owns bh in {xcd, xcd+8, xcd+16}
    const int id = blockIdx.x;
    const int idx = id >> 3;
    const int bh = (id & 7) + ((idx % 3) << 3);
    const int q0 = (idx / 3) << 6;
    const int b = bh / NH, h = bh - b * NH;
    const size_t hoff = (size_t)bh * NSEQ * HD;
    const short* qp = qb + hoff;     // [N][64]
    const short* kp = kb + hoff;     // [N][64]
    const short* vp = vt + hoff;     // [64][N]
    const int* mp = mask + b * NSEQ;
    const int kslice = wid * 16 + l16;       // K-row this lane loads
    const int kbase  = wid * 16 + quad * 4;  // first key this lane's P covers

    // Q fragments (B-operand, all 64 queries), loop-invariant
    bf16x8 qf[4][2];
    #pragma unroll
    for (int jt = 0; jt < 4; ++jt) {
        const short* qr = qp + (size_t)(q0 + jt*16 + l16) * HD + quad*8;
        qf[jt][0] = *(const bf16x8*)qr;
        qf[jt][1] = *(const bf16x8*)(qr + 32);
    }

    f32x4 o_acc[4][4] = {};
    float l[4] = {0.f, 0.f, 0.f, 0.f};

    // ping-pong register tiles
    bf16x8 Ak00, Ak01, Ak10, Ak11, Bk00, Bk01, Bk10, Bk11;
    bf16x4 Avl[4], Avh[4], Bvl[4], Bvh[4];
    int4 Am0, Am1, Bm0, Bm1;

    LOADT(0, Ak00,Ak01,Ak10,Ak11, Avl,Avh, Am0,Am1);
    for (int kt = 0; kt < NSEQ; kt += 256) {
        LOADT(kt + 128, Bk00,Bk01,Bk10,Bk11, Bvl,Bvh, Bm0,Bm1);
        BODYT(Ak00,Ak01,Ak10,Ak11, Avl,Avh, Am0,Am1);
        LOADT((kt + 256) & (NSEQ - 1), Ak00,Ak01,Ak10,Ak11, Avl,Avh, Am0,Am1);
        BODYT(Bk00,Bk01,Bk10,Bk11, Bvl,Bvh, Bm0,Bm1);
    }

    // ---- epilogue (unchanged from v4) ----
    #pragma unroll
    for (int jt = 0; jt < 4; ++jt) {
        l[jt] += __shfl_xor(l[jt], 16);
        l[jt] += __shfl_xor(l[jt], 32);
        if (quad == 0) lsum[wid][jt*16 + l16] = l[jt];
    }
    for (int w = 0; w < 4; ++w) {
        __syncthreads();
        if (wid == w) {
            #pragma unroll
            for (int it = 0; it < 4; ++it)
                #pragma unroll
                for (int jt = 0; jt < 4; ++jt)
                    #pragma unroll
                    for (int r = 0; r < 4; ++r) {
                        if (w == 0)
                            Ob[it*16 + quad*4 + r][jt*16 + l16] = o_acc[it][jt][r];
                        else
                            Ob[it*16 + quad*4 + r][jt*16 + l16] += o_acc[it][jt][r];
                    }
        }
    }
    __syncthreads();

    {
        const int ql = t >> 2, dc = (t & 3) * 16;
        float inv = 1.0f / (((lsum[0][ql] + lsum[1][ql]) +
                             (lsum[2][ql] + lsum[3][ql])));
        bf16x8 o8a, o8b;
        #pragma unroll
        for (int d = 0; d < 8; ++d) o8a[d] = f2b(Ob[dc + d][ql] * inv);
        #pragma unroll
        for (int d = 0; d < 8; ++d) o8b[d] = f2b(Ob[dc + 8 + d][ql] * inv);
        int tok = b * NSEQ + q0 + ql;
        short* dst = ao + (size_t)tok * CDIM + h * HD + dc;
        *(bf16x8*)dst = o8a;
        *(bf16x8*)(dst + 8) = o8b;
    }
}

// ---------------------------------------------------------------------------
// GEMM2 (unchanged from round 4)
// ---------------------------------------------------------------------------
__global__ __launch_bounds__(256) void gemm_proj(
    const short* __restrict__ A /*wpt[768][768]*/,
    const short* __restrict__ B /*ao [4096][768]*/,
    const float* __restrict__ bias, float* __restrict__ out)
{
    __shared__ short As[128 * 32];
    __shared__ short Bs[128 * 32];
    const int t = threadIdx.x;
    const int lane = t & 63, wid = t >> 6;
    const int quad = lane >> 4, l16 = lane & 15;
    const int wA = wid >> 1, wB = wid & 1;
    const int n0 = blockIdx.x * 128;
    const int m0 = blockIdx.y * 128;

    const int srow = wid * 16 + (lane >> 2), schunk = (lane & 3) * 8;
    const short* ag0 = A + (size_t)(n0 + srow) * CDIM + schunk;
    const short* ag1 = ag0 + (size_t)64 * CDIM;
    const short* bg0 = B + (size_t)(m0 + srow) * CDIM + schunk;
    const short* bg1 = bg0 + (size_t)64 * CDIM;
    short* asl0 = &As[(wid * 16) * 32];
    short* asl1 = &As[(wid * 16 + 64) * 32];
    short* bsl0 = &Bs[(wid * 16) * 32];
    short* bsl1 = &Bs[(wid * 16 + 64) * 32];

    f32x4 acc[4][4] = {};
    for (int k0 = 0; k0 < CDIM; k0 += 32) {
        __syncthreads();
        gll16(ag0 + k0, asl0);
        gll16(ag1 + k0, asl1);
        gll16(bg0 + k0, bsl0);
        gll16(bg1 + k0, bsl1);
        __syncthreads();
        bf16x8 af[4], bf[4];
        #pragma unroll
        for (int i = 0; i < 4; ++i)
            af[i] = *(const bf16x8*)&As[(wA*64 + i*16 + l16) * 32 + quad*8];
        #pragma unroll
        for (int j = 0; j < 4; ++j)
            bf[j] = *(const bf16x8*)&Bs[(wB*64 + j*16 + l16) * 32 + quad*8];
        #pragma unroll
        for (int i = 0; i < 4; ++i)
            #pragma unroll
            for (int j = 0; j < 4; ++j)
                acc[i][j] = MFMA16(af[i], bf[j], acc[i][j]);
    }

    #pragma unroll
    for (int i = 0; i < 4; ++i) {
        int col0 = n0 + wA*64 + i*16 + quad*4;
        float4 bias4 = *(const float4*)&bias[col0];
        #pragma unroll
        for (int j = 0; j < 4; ++j) {
            int tok = m0 + wB*64 + j*16 + l16;
            float4 o = { acc[i][j][0] + bias4.x, acc[i][j][1] + bias4.y,
                         acc[i][j][2] + bias4.z, acc[i][j][3] + bias4.w };
            *(float4*)(out + (size_t)tok * CDIM + col0) = o;
        }
    }
}

extern "C" void kernel_launch(void* const* d_in, const int* in_sizes, int n_in,
                              void* d_out, int out_size, void* d_ws, size_t ws_size,
                              hipStream_t stream)
{
    const float* x      = (const float*)d_in[0];
    const int*   mask   = (const int*)d_in[1];
    const float* w_qkv  = (const float*)d_in[2];
    const float* w_proj = (const float*)d_in[3];
    const float* b_proj = (const float*)d_in[4];
    float* out = (float*)d_out;

    const size_t SZ = (size_t)NTOK * CDIM;       // 3,145,728
    short* xb  = (short*)d_ws;                   // [4096][768]
    short* wqt = xb  + SZ;                       // [2304][768]
    short* wpt = wqt + (size_t)QKV_COLS * CDIM;  // [768][768]
    short* qb  = wpt + (size_t)CDIM * CDIM;      // [BH][N][64]
    short* kb  = qb  + SZ;                       // [BH][N][64]
    short* vt  = kb  + SZ;                       // [BH][64][N]
    short* ao  = vt  + SZ;                       // [4096][768]

    dim3 blk(256);
    convert_f32_bf16<<<(SZ/4 + 255)/256, blk, 0, stream>>>(x, xb, (int)(SZ/4));
    transpose_f32_bf16<<<dim3(QKV_COLS/32, CDIM/32), blk, 0, stream>>>(w_qkv, wqt, CDIM, QKV_COLS);
    transpose_f32_bf16<<<dim3(CDIM/32, CDIM/32),     blk, 0, stream>>>(w_proj, wpt, CDIM, CDIM);
    gemm_qkv<<<dim3(QKV_COLS/128, NTOK/128), blk, 0, stream>>>(wqt, xb, qb, kb, vt);
    attn_kernel<<<dim3(NBLK), blk, 0, stream>>>(qb, kb, vt, mask, ao);
    gemm_proj<<<dim3(CDIM/128, NTOK/128), blk, 0, stream>>>(wpt, ao, b_proj, out);
}

// Round 6
// 180.742 us; speedup vs baseline: 1.7271x; 1.1753x over previous
//
#include <hip/hip_runtime.h>
#include <cstdint>

#define NB 2
#define NSEQ 2048
#define CDIM 768
#define NH 12
#define HD 64
#define NTOK (NB*NSEQ)        // 4096
#define QKV_COLS (3*CDIM)     // 2304
#define NBLK ((NSEQ/64)*NH*NB) // 768 attn blocks

typedef short bf16x8 __attribute__((ext_vector_type(8)));   // 8 bf16 = 4 VGPR
typedef short bf16x4 __attribute__((ext_vector_type(4)));
typedef float f32x4  __attribute__((ext_vector_type(4)));
typedef short short4v __attribute__((ext_vector_type(4)));
typedef unsigned int uint4v __attribute__((ext_vector_type(4)));

#define MFMA16(a,b,c) __builtin_amdgcn_mfma_f32_16x16x32_bf16(a,b,c,0,0,0)

__device__ __forceinline__ short f2b(float f) {
    uint32_t u = __builtin_bit_cast(uint32_t, f);
    u += 0x7fffu + ((u >> 16) & 1u);
    return (short)(u >> 16);
}
__device__ __forceinline__ unsigned pack2(float a, float b) {
    unsigned ua = __builtin_bit_cast(unsigned, a) + 0x7fffu;
    unsigned ub = __builtin_bit_cast(unsigned, b) + 0x7fffu;
    return __builtin_amdgcn_perm(ub, ua, 0x07060302u);
}
__device__ __forceinline__ void gll16(const short* g, short* l) {
    __builtin_amdgcn_global_load_lds(
        (const __attribute__((address_space(1))) unsigned int*)g,
        (__attribute__((address_space(3))) unsigned int*)l, 16, 0, 0);
}

// ---------------------------------------------------------------------------
__global__ __launch_bounds__(256) void convert_f32_bf16(
    const float* __restrict__ in, short* __restrict__ out, int n4)
{
    int i = blockIdx.x * 256 + threadIdx.x;
    if (i < n4) {
        float4 v = ((const float4*)in)[i];
        short4v o = { f2b(v.x), f2b(v.y), f2b(v.z), f2b(v.w) };
        ((short4v*)out)[i] = o;
    }
}

// ---------------------------------------------------------------------------
__global__ __launch_bounds__(256) void transpose_f32_bf16(
    const float* __restrict__ w, short* __restrict__ wt, int K, int NC)
{
    __shared__ float tile[32][33];
    const int n0 = blockIdx.x * 32, k0 = blockIdx.y * 32;
    const int t = threadIdx.x;
    #pragma unroll
    for (int i = 0; i < 4; ++i) {
        int idx = t + i * 256; int r = idx >> 5, c = idx & 31;
        tile[r][c] = w[(size_t)(k0 + r) * NC + n0 + c];
    }
    __syncthreads();
    #pragma unroll
    for (int i = 0; i < 4; ++i) {
        int idx = t + i * 256; int r = idx >> 5, c = idx & 31;
        wt[(size_t)(n0 + r) * K + k0 + c] = f2b(tile[c][r]);
    }
}

// ---------------------------------------------------------------------------
// GEMM1 (m97-style, unchanged from round 4)
// ---------------------------------------------------------------------------
__global__ __launch_bounds__(256) void gemm_qkv(
    const short* __restrict__ A /*wqt[2304][768]*/,
    const short* __restrict__ B /*xb [4096][768]*/,
    short* __restrict__ qb, short* __restrict__ kb, short* __restrict__ vt)
{
    __shared__ short As[128 * 32];
    __shared__ short Bs[128 * 32];
    const int t = threadIdx.x;
    const int lane = t & 63, wid = t >> 6;
    const int quad = lane >> 4, l16 = lane & 15;
    const int wA = wid >> 1, wB = wid & 1;
    const int n0 = blockIdx.x * 128;
    const int m0 = blockIdx.y * 128;

    const int srow = wid * 16 + (lane >> 2), schunk = (lane & 3) * 8;
    const short* ag0 = A + (size_t)(n0 + srow) * CDIM + schunk;
    const short* ag1 = ag0 + (size_t)64 * CDIM;
    const short* bg0 = B + (size_t)(m0 + srow) * CDIM + schunk;
    const short* bg1 = bg0 + (size_t)64 * CDIM;
    short* asl0 = &As[(wid * 16) * 32];
    short* asl1 = &As[(wid * 16 + 64) * 32];
    short* bsl0 = &Bs[(wid * 16) * 32];
    short* bsl1 = &Bs[(wid * 16 + 64) * 32];

    f32x4 acc[4][4] = {};
    for (int k0 = 0; k0 < CDIM; k0 += 32) {
        __syncthreads();
        gll16(ag0 + k0, asl0);
        gll16(ag1 + k0, asl1);
        gll16(bg0 + k0, bsl0);
        gll16(bg1 + k0, bsl1);
        __syncthreads();
        bf16x8 af[4], bf[4];
        #pragma unroll
        for (int i = 0; i < 4; ++i)
            af[i] = *(const bf16x8*)&As[(wA*64 + i*16 + l16) * 32 + quad*8];
        #pragma unroll
        for (int j = 0; j < 4; ++j)
            bf[j] = *(const bf16x8*)&Bs[(wB*64 + j*16 + l16) * 32 + quad*8];
        #pragma unroll
        for (int i = 0; i < 4; ++i)
            #pragma unroll
            for (int j = 0; j < 4; ++j)
                acc[i][j] = MFMA16(af[i], bf[j], acc[i][j]);
    }

    const int colbase = n0 + wA * 64;
    const int s = colbase / CDIM;
    const int h = (colbase - s * CDIM) >> 6;
    const int b = m0 >> 11;
    const size_t bh = (size_t)(b * NH + h);
    #pragma unroll
    for (int i = 0; i < 4; ++i) {
        const int d0 = i*16 + quad*4;
        #pragma unroll
        for (int j = 0; j < 4; ++j) {
            int tok = (m0 + wB*64 + j*16 + l16) & (NSEQ - 1);
            if (s < 2) {
                short* dst = (s == 0 ? qb : kb) + (bh * NSEQ + tok) * HD + d0;
                short4v o = { f2b(acc[i][j][0]), f2b(acc[i][j][1]),
                              f2b(acc[i][j][2]), f2b(acc[i][j][3]) };
                *(short4v*)dst = o;
            } else {
                short* dst = vt + (bh * HD + d0) * NSEQ + tok;
                #pragma unroll
                for (int r = 0; r < 4; ++r)
                    dst[(size_t)r * NSEQ] = f2b(acc[i][j][r]);
            }
        }
    }
}

// ---------------------------------------------------------------------------
// Flash attention v6: cooperative global_load_lds staging of K(128x64) and
// V(64x128) tiles with XOR-chunk swizzle (swizzle applied on the GLOBAL
// address decode so gll16's contiguous-dest constraint holds; LDS reads are
// bank-balanced). P stays in registers (S^T = K·Q^T trick, 128-key fusion).
// 2 barriers per 128-key iteration. Epilogue LDS aliases the staging buffers.
// ---------------------------------------------------------------------------
__global__ __launch_bounds__(256, 3) void attn_kernel(
    const short* __restrict__ qb, const short* __restrict__ kb,
    const short* __restrict__ vt, const int* __restrict__ mask,
    short* __restrict__ ao)
{
    __shared__ __align__(16) char smem[32768];
    short* KsB = (short*)smem;             // 16 KB: K rows [key 0..127][d 0..63]
    short* VsB = (short*)(smem + 16384);   // 16 KB: V rows [d 0..63][key 0..127]
    float (*Ob)[68] = (float(*)[68])smem;              // epilogue alias
    float (*lsum)[64] = (float(*)[64])(smem + 17408);  // epilogue alias

    const int t = threadIdx.x;
    const int lane = t & 63, wid = t >> 6;
    const int quad = lane >> 4, l16 = lane & 15;
    // XCD swizzle: XCD = id%8 owns bh in {xcd, xcd+8, xcd+16}
    const int id = blockIdx.x;
    const int idx = id >> 3;
    const int bh = (id & 7) + ((idx % 3) << 3);
    const int q0 = (idx / 3) << 6;
    const int b = bh / NH, h = bh - b * NH;
    const size_t hoff = (size_t)bh * NSEQ * HD;
    const short* qp = qb + hoff;     // [N][64]
    const short* kp = kb + hoff;     // [N][64]
    const short* vp = vt + hoff;     // [64][N]
    const int* mp = mask + b * NSEQ;
    const int kbase = wid * 16 + quad * 4;   // lane's first key within a tile

    // staging decode (swizzled): LDS byte o = wid*4096 + j*1024 + lane*16
    int rK[4], cK[4], dV[4], cV[4];
    short *ldsK[4], *ldsV[4];
    #pragma unroll
    for (int j = 0; j < 4; ++j) {
        int o = wid * 4096 + j * 1024 + lane * 16;
        rK[j] = o >> 7;                         // K row (key)
        cK[j] = ((o >> 4) & 7) ^ (rK[j] & 7);   // global 16B chunk
        dV[j] = o >> 8;                         // V row (d)
        cV[j] = ((o >> 4) & 15) ^ (dV[j] & 15);
        ldsK[j] = KsB + (wid * 4096 + j * 1024) / 2;
        ldsV[j] = VsB + (wid * 4096 + j * 1024) / 2;
    }

    // Q fragments (B-operand, all 64 queries), loop-invariant
    bf16x8 qf[4][2];
    #pragma unroll
    for (int jt = 0; jt < 4; ++jt) {
        const short* qr = qp + (size_t)(q0 + jt*16 + l16) * HD + quad*8;
        qf[jt][0] = *(const bf16x8*)qr;
        qf[jt][1] = *(const bf16x8*)(qr + 32);
    }

    f32x4 o_acc[4][4] = {};
    float l[4] = {0.f, 0.f, 0.f, 0.f};

    // read-side swizzle constants
    const int r7 = l16 & 7;
    const int krow = (wid * 16 + l16) * 64;           // shorts
    const int kc0 = ((quad     ^ r7) << 3);
    const int kc1 = (((quad+4) ^ r7) << 3);
    const int vposl = ((wid*2 + (quad >> 1)) ^ l16) << 3;
    const int vposh = (((8 + wid*2 + (quad >> 1)) ^ l16) << 3);
    const int vsub = (quad & 1) * 4;

    for (int kt = 0; kt < NSEQ; kt += 128) {
        __syncthreads();   // prev body's LDS reads done
        #pragma unroll
        for (int j = 0; j < 4; ++j) {
            gll16(kp + (size_t)(kt + rK[j]) * HD + cK[j]*8, ldsK[j]);
            gll16(vp + (size_t)dV[j] * NSEQ + kt + cV[j]*8, ldsV[j]);
        }
        int4 mi0 = *(const int4*)(mp + kt + kbase);
        int4 mi1 = *(const int4*)(mp + kt + 64 + kbase);
        __syncthreads();   // vmcnt drain lands staged data

        // ---- S phase: two 64-key tiles, wave's 16-key slice each ----
        bf16x8 kf00 = *(const bf16x8*)&KsB[krow + kc0];
        bf16x8 kf01 = *(const bf16x8*)&KsB[krow + kc1];
        bf16x8 kf10 = *(const bf16x8*)&KsB[4096 + krow + kc0];
        bf16x8 kf11 = *(const bf16x8*)&KsB[4096 + krow + kc1];
        f32x4 s0[4] = {}, s1[4] = {};
        #pragma unroll
        for (int jt = 0; jt < 4; ++jt) {
            s0[jt] = MFMA16(kf00, qf[jt][0], s0[jt]);
            s0[jt] = MFMA16(kf01, qf[jt][1], s0[jt]);
            s1[jt] = MFMA16(kf10, qf[jt][0], s1[jt]);
            s1[jt] = MFMA16(kf11, qf[jt][1], s1[jt]);
        }

        // ---- mask, exp (faithful: no max-sub), rowsum partial, pack ----
        float4 m0 = {(float)mi0.x, (float)mi0.y, (float)mi0.z, (float)mi0.w};
        float4 m1 = {(float)mi1.x, (float)mi1.y, (float)mi1.z, (float)mi1.w};
        bf16x8 pb[4];
        #pragma unroll
        for (int jt = 0; jt < 4; ++jt) {
            float e0 = __expf(s0[jt][0] * 0.125f) * m0.x;
            float e1 = __expf(s0[jt][1] * 0.125f) * m0.y;
            float e2 = __expf(s0[jt][2] * 0.125f) * m0.z;
            float e3 = __expf(s0[jt][3] * 0.125f) * m0.w;
            float f0 = __expf(s1[jt][0] * 0.125f) * m1.x;
            float f1 = __expf(s1[jt][1] * 0.125f) * m1.y;
            float f2 = __expf(s1[jt][2] * 0.125f) * m1.z;
            float f3 = __expf(s1[jt][3] * 0.125f) * m1.w;
            l[jt] += ((e0 + e1) + (e2 + e3)) + ((f0 + f1) + (f2 + f3));
            uint4v pk = { pack2(e0, e1), pack2(e2, e3),
                          pack2(f0, f1), pack2(f2, f3) };
            pb[jt] = __builtin_bit_cast(bf16x8, pk);
        }

        // ---- PV: A = V^T frags from LDS (keys match pb's k-perm) ----
        #pragma unroll
        for (int it = 0; it < 4; ++it) {
            const int vrow = (it*16 + l16) * 128;
            bf16x4 lo = *(const bf16x4*)&VsB[vrow + vposl + vsub];
            bf16x4 hi = *(const bf16x4*)&VsB[vrow + vposh + vsub];
            bf16x8 vf = __builtin_shufflevector(lo, hi, 0,1,2,3,4,5,6,7);
            #pragma unroll
            for (int jt = 0; jt < 4; ++jt)
                o_acc[it][jt] = MFMA16(vf, pb[jt], o_acc[it][jt]);
        }
    }

    // ---- epilogue (smem re-aliased; barrier before overwriting staging) ----
    __syncthreads();
    #pragma unroll
    for (int jt = 0; jt < 4; ++jt) {
        l[jt] += __shfl_xor(l[jt], 16);
        l[jt] += __shfl_xor(l[jt], 32);
        if (quad == 0) lsum[wid][jt*16 + l16] = l[jt];
    }
    for (int w = 0; w < 4; ++w) {
        __syncthreads();
        if (wid == w) {
            #pragma unroll
            for (int it = 0; it < 4; ++it)
                #pragma unroll
                for (int jt = 0; jt < 4; ++jt)
                    #pragma unroll
                    for (int r = 0; r < 4; ++r) {
                        if (w == 0)
                            Ob[it*16 + quad*4 + r][jt*16 + l16] = o_acc[it][jt][r];
                        else
                            Ob[it*16 + quad*4 + r][jt*16 + l16] += o_acc[it][jt][r];
                    }
        }
    }
    __syncthreads();

    {
        const int ql = t >> 2, dc = (t & 3) * 16;
        float inv = 1.0f / (((lsum[0][ql] + lsum[1][ql]) +
                             (lsum[2][ql] + lsum[3][ql])));
        bf16x8 o8a, o8b;
        #pragma unroll
        for (int d = 0; d < 8; ++d) o8a[d] = f2b(Ob[dc + d][ql] * inv);
        #pragma unroll
        for (int d = 0; d < 8; ++d) o8b[d] = f2b(Ob[dc + 8 + d][ql] * inv);
        int tok = b * NSEQ + q0 + ql;
        short* dst = ao + (size_t)tok * CDIM + h * HD + dc;
        *(bf16x8*)dst = o8a;
        *(bf16x8*)(dst + 8) = o8b;
    }
}

// ---------------------------------------------------------------------------
// GEMM2 (unchanged from round 4)
// ---------------------------------------------------------------------------
__global__ __launch_bounds__(256) void gemm_proj(
    const short* __restrict__ A /*wpt[768][768]*/,
    const short* __restrict__ B /*ao [4096][768]*/,
    const float* __restrict__ bias, float* __restrict__ out)
{
    __shared__ short As[128 * 32];
    __shared__ short Bs[128 * 32];
    const int t = threadIdx.x;
    const int lane = t & 63, wid = t >> 6;
    const int quad = lane >> 4, l16 = lane & 15;
    const int wA = wid >> 1, wB = wid & 1;
    const int n0 = blockIdx.x * 128;
    const int m0 = blockIdx.y * 128;

    const int srow = wid * 16 + (lane >> 2), schunk = (lane & 3) * 8;
    const short* ag0 = A + (size_t)(n0 + srow) * CDIM + schunk;
    const short* ag1 = ag0 + (size_t)64 * CDIM;
    const short* bg0 = B + (size_t)(m0 + srow) * CDIM + schunk;
    const short* bg1 = bg0 + (size_t)64 * CDIM;
    short* asl0 = &As[(wid * 16) * 32];
    short* asl1 = &As[(wid * 16 + 64) * 32];
    short* bsl0 = &Bs[(wid * 16) * 32];
    short* bsl1 = &Bs[(wid * 16 + 64) * 32];

    f32x4 acc[4][4] = {};
    for (int k0 = 0; k0 < CDIM; k0 += 32) {
        __syncthreads();
        gll16(ag0 + k0, asl0);
        gll16(ag1 + k0, asl1);
        gll16(bg0 + k0, bsl0);
        gll16(bg1 + k0, bsl1);
        __syncthreads();
        bf16x8 af[4], bf[4];
        #pragma unroll
        for (int i = 0; i < 4; ++i)
            af[i] = *(const bf16x8*)&As[(wA*64 + i*16 + l16) * 32 + quad*8];
        #pragma unroll
        for (int j = 0; j < 4; ++j)
            bf[j] = *(const bf16x8*)&Bs[(wB*64 + j*16 + l16) * 32 + quad*8];
        #pragma unroll
        for (int i = 0; i < 4; ++i)
            #pragma unroll
            for (int j = 0; j < 4; ++j)
                acc[i][j] = MFMA16(af[i], bf[j], acc[i][j]);
    }

    #pragma unroll
    for (int i = 0; i < 4; ++i) {
        int col0 = n0 + wA*64 + i*16 + quad*4;
        float4 bias4 = *(const float4*)&bias[col0];
        #pragma unroll
        for (int j = 0; j < 4; ++j) {
            int tok = m0 + wB*64 + j*16 + l16;
            float4 o = { acc[i][j][0] + bias4.x, acc[i][j][1] + bias4.y,
                         acc[i][j][2] + bias4.z, acc[i][j][3] + bias4.w };
            *(float4*)(out + (size_t)tok * CDIM + col0) = o;
        }
    }
}

extern "C" void kernel_launch(void* const* d_in, const int* in_sizes, int n_in,
                              void* d_out, int out_size, void* d_ws, size_t ws_size,
                              hipStream_t stream)
{
    const float* x      = (const float*)d_in[0];
    const int*   mask   = (const int*)d_in[1];
    const float* w_qkv  = (const float*)d_in[2];
    const float* w_proj = (const float*)d_in[3];
    const float* b_proj = (const float*)d_in[4];
    float* out = (float*)d_out;

    const size_t SZ = (size_t)NTOK * CDIM;       // 3,145,728
    short* xb  = (short*)d_ws;                   // [4096][768]
    short* wqt = xb  + SZ;                       // [2304][768]
    short* wpt = wqt + (size_t)QKV_COLS * CDIM;  // [768][768]
    short* qb  = wpt + (size_t)CDIM * CDIM;      // [BH][N][64]
    short* kb  = qb  + SZ;                       // [BH][N][64]
    short* vt  = kb  + SZ;                       // [BH][64][N]
    short* ao  = vt  + SZ;                       // [4096][768]

    dim3 blk(256);
    convert_f32_bf16<<<(SZ/4 + 255)/256, blk, 0, stream>>>(x, xb, (int)(SZ/4));
    transpose_f32_bf16<<<dim3(QKV_COLS/32, CDIM/32), blk, 0, stream>>>(w_qkv, wqt, CDIM, QKV_COLS);
    transpose_f32_bf16<<<dim3(CDIM/32, CDIM/32),     blk, 0, stream>>>(w_proj, wpt, CDIM, CDIM);
    gemm_qkv<<<dim3(QKV_COLS/128, NTOK/128), blk, 0, stream>>>(wqt, xb, qb, kb, vt);
    attn_kernel<<<dim3(NBLK), blk, 0, stream>>>(qb, kb, vt, mask, ao);
    gemm_proj<<<dim3(CDIM/128, NTOK/128), blk, 0, stream>>>(wpt, ao, b_proj, out);
}